// Round 1
// baseline (429.568 us; speedup 1.0000x reference)
//
#include <hip/hip_runtime.h>
#include <cfloat>

#define FIN 256
#define FOUT 64
#define NH 4
#define NEG_SLOPE 0.2f

// ---------------------------------------------------------------------------
// K1: h_prime[h][n][f] = sum_k h[n][k] * w[h][k][f]    (fp32 vector GEMM)
//     s_src[h][n] = h_prime[h][n][:] . fc[h][0:64]
//     s_dst[h][n] = h_prime[h][n][:] . fc[h][64:128]
// block = 256 threads = 4 waves (one per head); 8 nodes per block.
// ---------------------------------------------------------------------------
__global__ __launch_bounds__(256) void k_gemm(
    const float* __restrict__ h, const float* __restrict__ w,
    const float* __restrict__ fc, float* __restrict__ h_prime,
    float* __restrict__ s_src, float* __restrict__ s_dst, int N)
{
    __shared__ float4 ht4[8 * (FIN / 4)];   // [node][k/4], 8 KiB
    const int tid = threadIdx.x;
    const int n0 = blockIdx.x * 8;

    // cooperative load of 8 node rows (8 x 256 floats) as float4
    for (int j = tid; j < 8 * (FIN / 4); j += 256) {
        const int row = j >> 6;       // FIN/4 = 64 float4 per row
        const int kq  = j & 63;
        const int n   = n0 + row;
        float4 v = make_float4(0.f, 0.f, 0.f, 0.f);
        if (n < N) v = ((const float4*)(h + (size_t)n * FIN))[kq];
        ht4[j] = v;
    }
    __syncthreads();

    const int head = tid >> 6;
    const int lane = tid & 63;
    const float* wh = w + (size_t)head * FIN * FOUT;
    const float a_s = fc[head * 2 * FOUT + lane];
    const float a_d = fc[head * 2 * FOUT + FOUT + lane];

    float acc[8];
#pragma unroll
    for (int i = 0; i < 8; ++i) acc[i] = 0.f;

    for (int kt = 0; kt < FIN; kt += 32) {
        float wr[32];
#pragma unroll
        for (int kk = 0; kk < 32; ++kk)
            wr[kk] = wh[(size_t)(kt + kk) * FOUT + lane];
#pragma unroll
        for (int i = 0; i < 8; ++i) {
#pragma unroll
            for (int kq = 0; kq < 8; ++kq) {
                const float4 hv = ht4[i * 64 + (kt >> 2) + kq];
                acc[i] = fmaf(hv.x, wr[kq * 4 + 0], acc[i]);
                acc[i] = fmaf(hv.y, wr[kq * 4 + 1], acc[i]);
                acc[i] = fmaf(hv.z, wr[kq * 4 + 2], acc[i]);
                acc[i] = fmaf(hv.w, wr[kq * 4 + 3], acc[i]);
            }
        }
    }

#pragma unroll
    for (int i = 0; i < 8; ++i) {
        const int n = n0 + i;
        if (n < N) {
            const float v = acc[i];
            h_prime[((size_t)head * N + n) * FOUT + lane] = v;
            float ps = v * a_s;
            float pd = v * a_d;
#pragma unroll
            for (int d = 32; d; d >>= 1) {
                ps += __shfl_xor(ps, d);
                pd += __shfl_xor(pd, d);
            }
            if (lane == 0) {
                s_src[(size_t)head * N + n] = ps;
                s_dst[(size_t)head * N + n] = pd;
            }
        }
    }
}

// ---------------------------------------------------------------------------
// CSR build: histogram -> hierarchical exclusive scan -> scatter
// ---------------------------------------------------------------------------
__global__ void k_hist(const int* __restrict__ ei, int E, int* __restrict__ cnt)
{
    const int e = blockIdx.x * blockDim.x + threadIdx.x;
    if (e < E) atomicAdd(&cnt[ei[e]], 1);
}

__global__ __launch_bounds__(1024) void k_scan_a(
    const int* __restrict__ cnt, int N, int* __restrict__ excl,
    int* __restrict__ bsum)
{
    __shared__ int wsum[16];
    const int tid  = threadIdx.x;
    const int i    = blockIdx.x * 1024 + tid;
    const int lane = tid & 63;
    const int wid  = tid >> 6;
    const int v = (i < N) ? cnt[i] : 0;
    int x = v;
#pragma unroll
    for (int d = 1; d < 64; d <<= 1) {
        const int t = __shfl_up(x, d);
        if (lane >= d) x += t;
    }
    if (lane == 63) wsum[wid] = x;
    __syncthreads();
    if (wid == 0) {
        const int t = (lane < 16) ? wsum[lane] : 0;
        int y = t;
#pragma unroll
        for (int d = 1; d < 16; d <<= 1) {
            const int u = __shfl_up(y, d);
            if (lane >= d) y += u;
        }
        if (lane < 16) wsum[lane] = y - t;  // exclusive wave offsets
    }
    __syncthreads();
    x += wsum[wid];
    if (i < N) excl[i] = x - v;
    if (tid == 1023) bsum[blockIdx.x] = x;
}

__global__ __launch_bounds__(64) void k_scan_b(
    const int* __restrict__ bsum, int nb, int* __restrict__ boffs)
{
    const int lane = threadIdx.x;
    int carry = 0;
    for (int base = 0; base < nb; base += 64) {
        const int idx = base + lane;
        const int v = (idx < nb) ? bsum[idx] : 0;
        int x = v;
#pragma unroll
        for (int d = 1; d < 64; d <<= 1) {
            const int t = __shfl_up(x, d);
            if (lane >= d) x += t;
        }
        if (idx < nb) boffs[idx] = carry + x - v;
        carry += __shfl(x, 63);
    }
}

__global__ void k_addback(int* __restrict__ excl, const int* __restrict__ boffs,
                          int N, int* __restrict__ cursor)
{
    const int i = blockIdx.x * blockDim.x + threadIdx.x;
    if (i < N) {
        const int v = excl[i] + boffs[i >> 10];
        excl[i] = v;
        cursor[i] = v;
    }
}

__global__ void k_scatter(const int* __restrict__ ei, int E,
                          int* __restrict__ cursor, int* __restrict__ col)
{
    const int e = blockIdx.x * blockDim.x + threadIdx.x;
    if (e < E) {
        const int s = ei[e];
        const int d = ei[E + e];
        const int pos = atomicAdd(&cursor[s], 1);
        col[pos] = d;
    }
}

// ---------------------------------------------------------------------------
// K5: per-node segment softmax + weighted aggregation.
// block = 256 threads = 4 waves (one per head); one block per node n (= src).
// lane = output feature.
// ---------------------------------------------------------------------------
__global__ __launch_bounds__(256) void k_agg(
    const int* __restrict__ row_start, const int* __restrict__ cnt,
    const int* __restrict__ col, const float* __restrict__ h_prime,
    const float* __restrict__ s_src, const float* __restrict__ s_dst,
    const float* __restrict__ bias, float* __restrict__ out, int N)
{
    __shared__ float l_alpha[NH][64];
    __shared__ int   l_dst[NH][64];
    __shared__ float l_acc[NH][64];

    const int n     = blockIdx.x;
    const int head  = threadIdx.x >> 6;
    const int lane  = threadIdx.x & 63;
    const int start = row_start[n];
    const int deg   = cnt[n];

    const float ssn = s_src[(size_t)head * N + n];
    const float* sdh = s_dst + (size_t)head * N;

    // pass 1: segment max
    float m = -FLT_MAX;
    for (int j0 = 0; j0 < deg; j0 += 64) {
        const int j = j0 + lane;
        float sc = -FLT_MAX;
        if (j < deg) {
            const int d = col[start + j];
            float x = ssn + sdh[d];
            sc = (x >= 0.f) ? x : NEG_SLOPE * x;
        }
        m = fmaxf(m, sc);
    }
#pragma unroll
    for (int d = 32; d; d >>= 1) m = fmaxf(m, __shfl_xor(m, d));

    // pass 2: denom
    float sum = 0.f;
    for (int j0 = 0; j0 < deg; j0 += 64) {
        const int j = j0 + lane;
        if (j < deg) {
            const int d = col[start + j];
            float x = ssn + sdh[d];
            x = (x >= 0.f) ? x : NEG_SLOPE * x;
            sum += __expf(x - m);
        }
    }
#pragma unroll
    for (int d = 32; d; d >>= 1) sum += __shfl_xor(sum, d);
    const float inv_denom = 1.0f / sum;

    // pass 3: alpha-weighted gather of h_prime rows
    float acc = 0.f;
    const float* hp = h_prime + (size_t)head * N * FOUT;
    for (int j0 = 0; j0 < deg; j0 += 64) {
        const int j = j0 + lane;
        const int chunk = min(64, deg - j0);
        if (j < deg) {
            const int d = col[start + j];
            float x = ssn + sdh[d];
            x = (x >= 0.f) ? x : NEG_SLOPE * x;
            l_alpha[head][lane] = __expf(x - m) * inv_denom;
            l_dst[head][lane] = d;
        }
        for (int jj = 0; jj < chunk; ++jj) {
            const float a = l_alpha[head][jj];
            const int  dd = l_dst[head][jj];
            acc = fmaf(a, hp[(size_t)dd * FOUT + lane], acc);
        }
    }

    l_acc[head][lane] = acc;
    __syncthreads();
    if (head == 0) {
        const float o = (l_acc[0][lane] + l_acc[1][lane] +
                         l_acc[2][lane] + l_acc[3][lane]) * 0.25f + bias[lane];
        out[(size_t)n * FOUT + lane] = o;
    }
}

// ---------------------------------------------------------------------------
extern "C" void kernel_launch(void* const* d_in, const int* in_sizes, int n_in,
                              void* d_out, int out_size, void* d_ws, size_t ws_size,
                              hipStream_t stream)
{
    const float* h    = (const float*)d_in[0];
    const int*   ei   = (const int*)d_in[1];
    const float* w    = (const float*)d_in[2];
    const float* fc   = (const float*)d_in[3];
    const float* bias = (const float*)d_in[4];
    float* out = (float*)d_out;

    const int N = in_sizes[0] / FIN;
    const int E = in_sizes[1] / 2;

    // workspace layout (all 16B-aligned chunks)
    char* ws = (char*)d_ws;
    auto take = [&](size_t bytes) {
        char* p = ws;
        ws += (bytes + 255) & ~(size_t)255;
        return p;
    };
    float* h_prime   = (float*)take((size_t)NH * N * FOUT * sizeof(float));
    float* s_src     = (float*)take((size_t)NH * N * sizeof(float));
    float* s_dst     = (float*)take((size_t)NH * N * sizeof(float));
    int*   cnt       = (int*)take((size_t)N * sizeof(int));
    int*   row_start = (int*)take((size_t)N * sizeof(int));
    int*   cursor    = (int*)take((size_t)N * sizeof(int));
    int*   col       = (int*)take((size_t)E * sizeof(int));
    const int nb = (N + 1023) / 1024;
    int*   bsum      = (int*)take((size_t)nb * sizeof(int));
    int*   boffs     = (int*)take((size_t)nb * sizeof(int));

    hipMemsetAsync(cnt, 0, (size_t)N * sizeof(int), stream);

    k_gemm<<<(N + 7) / 8, 256, 0, stream>>>(h, w, fc, h_prime, s_src, s_dst, N);
    k_hist<<<(E + 255) / 256, 256, 0, stream>>>(ei, E, cnt);
    k_scan_a<<<nb, 1024, 0, stream>>>(cnt, N, row_start, bsum);
    k_scan_b<<<1, 64, 0, stream>>>(bsum, nb, boffs);
    k_addback<<<(N + 255) / 256, 256, 0, stream>>>(row_start, boffs, N, cursor);
    k_scatter<<<(E + 255) / 256, 256, 0, stream>>>(ei, E, cursor, col);
    k_agg<<<N, 256, 0, stream>>>(row_start, cnt, col, h_prime, s_src, s_dst,
                                 bias, out, N);
}

// Round 2
// 343.536 us; speedup vs baseline: 1.2504x; 1.2504x over previous
//
#include <hip/hip_runtime.h>
#include <cfloat>

#define FIN 256
#define FOUT 64
#define NH 4
#define NEG_SLOPE 0.2f

typedef __bf16 bf16x8 __attribute__((ext_vector_type(8)));
typedef float f32x4 __attribute__((ext_vector_type(4)));

__device__ __forceinline__ ushort f2bf(float f) {
    return (ushort)((__float_as_uint(f) + 0x8000u) >> 16);  // round-half-up
}
__device__ __forceinline__ float bf2f(ushort u) {
    return __uint_as_float(((unsigned)u) << 16);
}

// ---------------------------------------------------------------------------
// K0: wt[h][col][k] (bf16) = w[h][k][col]  — 4*64*256 = 65536 elems
// ---------------------------------------------------------------------------
__global__ __launch_bounds__(256) void k_wconv(const float* __restrict__ w,
                                               ushort* __restrict__ wt)
{
    const int g = blockIdx.x * 256 + threadIdx.x;   // grid 256 -> exactly 65536
    const int hh  = g >> 14;
    const int rem = g & 16383;
    const int col = rem >> 8;
    const int k   = rem & 255;
    wt[g] = f2bf(w[(((hh << 8) | k) << 6) | col]);
}

// ---------------------------------------------------------------------------
// K1: bf16 MFMA GEMM. block = 256 = 4 waves (one head each), 64 nodes/block.
// Per wave: 4 m-tiles x 4 n-tiles x 8 k-steps of mfma_f32_16x16x32_bf16.
// Fused epilogue: h_prime (bf16) store + s_src/s_dst via 16-lane reduce.
// A/B layout: A[l&15][8*(l>>4)+j], B[8*(l>>4)+j][l&15]; C[(l>>4)*4+r][l&15].
// ---------------------------------------------------------------------------
#define ASTRIDE 280   // ushorts per LDS row: 560 B, 16B-aligned, conflict-free
__global__ __launch_bounds__(256) void k_gemm(
    const float* __restrict__ h, const ushort* __restrict__ wt,
    const float* __restrict__ fc, ushort* __restrict__ hp,
    float* __restrict__ s_src, float* __restrict__ s_dst, int N)
{
    __shared__ ushort Alds[64 * ASTRIDE];
    const int tid = threadIdx.x;
    const int n0 = blockIdx.x * 64;

    // stage A: 64 rows x 256 cols fp32 -> bf16 in LDS
    for (int idx = tid; idx < 64 * 64; idx += 256) {
        const int row  = idx >> 6;
        const int quad = idx & 63;
        const int n = n0 + row;
        float4 v = make_float4(0.f, 0.f, 0.f, 0.f);
        if (n < N) v = ((const float4*)(h + (size_t)n * FIN))[quad];
        ushort4 b;
        b.x = f2bf(v.x); b.y = f2bf(v.y); b.z = f2bf(v.z); b.w = f2bf(v.w);
        *(ushort4*)&Alds[row * ASTRIDE + quad * 4] = b;
    }
    __syncthreads();

    const int head = tid >> 6;
    const int lane = tid & 63;
    const int lrow = lane & 15;
    const int lq   = lane >> 4;

    const ushort* wth = wt + head * (64 * 256);

    f32x4 acc[4][4];
#pragma unroll
    for (int mt = 0; mt < 4; ++mt)
#pragma unroll
        for (int nt = 0; nt < 4; ++nt)
            acc[mt][nt] = (f32x4){0.f, 0.f, 0.f, 0.f};

#pragma unroll
    for (int kt = 0; kt < 8; ++kt) {
        const int kof = kt * 32 + lq * 8;
        bf16x8 af[4];
#pragma unroll
        for (int mt = 0; mt < 4; ++mt)
            af[mt] = *(const bf16x8*)&Alds[(mt * 16 + lrow) * ASTRIDE + kof];
#pragma unroll
        for (int nt = 0; nt < 4; ++nt) {
            const bf16x8 bfr = *(const bf16x8*)&wth[(nt * 16 + lrow) * 256 + kof];
#pragma unroll
            for (int mt = 0; mt < 4; ++mt)
                acc[mt][nt] = __builtin_amdgcn_mfma_f32_16x16x32_bf16(
                    af[mt], bfr, acc[mt][nt], 0, 0, 0);
        }
    }

    // epilogue
    float as_[4], ad_[4];
#pragma unroll
    for (int nt = 0; nt < 4; ++nt) {
        as_[nt] = fc[head * 2 * FOUT + nt * 16 + lrow];
        ad_[nt] = fc[head * 2 * FOUT + FOUT + nt * 16 + lrow];
    }
#pragma unroll
    for (int mt = 0; mt < 4; ++mt) {
        const int rbase = n0 + mt * 16 + lq * 4;
#pragma unroll
        for (int r = 0; r < 4; ++r) {
            const int n = rbase + r;
            float ps = 0.f, pd = 0.f;
#pragma unroll
            for (int nt = 0; nt < 4; ++nt) {
                const float v = acc[mt][nt][r];
                ps = fmaf(v, as_[nt], ps);
                pd = fmaf(v, ad_[nt], pd);
                if (n < N)
                    hp[((size_t)head * N + n) * FOUT + nt * 16 + lrow] = f2bf(v);
            }
            ps += __shfl_xor(ps, 1); pd += __shfl_xor(pd, 1);
            ps += __shfl_xor(ps, 2); pd += __shfl_xor(pd, 2);
            ps += __shfl_xor(ps, 4); pd += __shfl_xor(pd, 4);
            ps += __shfl_xor(ps, 8); pd += __shfl_xor(pd, 8);
            if (lrow == 0 && n < N) {
                s_src[(size_t)head * N + n] = ps;
                s_dst[(size_t)head * N + n] = pd;
            }
        }
    }
}

// ---------------------------------------------------------------------------
// CSR build: histogram -> hierarchical exclusive scan -> scatter
// ---------------------------------------------------------------------------
__global__ void k_hist(const int* __restrict__ ei, int E, int* __restrict__ cnt)
{
    const int e = blockIdx.x * blockDim.x + threadIdx.x;
    if (e < E) atomicAdd(&cnt[ei[e]], 1);
}

__global__ __launch_bounds__(1024) void k_scan_a(
    const int* __restrict__ cnt, int N, int* __restrict__ excl,
    int* __restrict__ bsum)
{
    __shared__ int wsum[16];
    const int tid  = threadIdx.x;
    const int i    = blockIdx.x * 1024 + tid;
    const int lane = tid & 63;
    const int wid  = tid >> 6;
    const int v = (i < N) ? cnt[i] : 0;
    int x = v;
#pragma unroll
    for (int d = 1; d < 64; d <<= 1) {
        const int t = __shfl_up(x, d);
        if (lane >= d) x += t;
    }
    if (lane == 63) wsum[wid] = x;
    __syncthreads();
    if (wid == 0) {
        const int t = (lane < 16) ? wsum[lane] : 0;
        int y = t;
#pragma unroll
        for (int d = 1; d < 16; d <<= 1) {
            const int u = __shfl_up(y, d);
            if (lane >= d) y += u;
        }
        if (lane < 16) wsum[lane] = y - t;
    }
    __syncthreads();
    x += wsum[wid];
    if (i < N) excl[i] = x - v;
    if (tid == 1023) bsum[blockIdx.x] = x;
}

__global__ __launch_bounds__(64) void k_scan_b(
    const int* __restrict__ bsum, int nb, int* __restrict__ boffs)
{
    const int lane = threadIdx.x;
    int carry = 0;
    for (int base = 0; base < nb; base += 64) {
        const int idx = base + lane;
        const int v = (idx < nb) ? bsum[idx] : 0;
        int x = v;
#pragma unroll
        for (int d = 1; d < 64; d <<= 1) {
            const int t = __shfl_up(x, d);
            if (lane >= d) x += t;
        }
        if (idx < nb) boffs[idx] = carry + x - v;
        carry += __shfl(x, 63);
    }
}

__global__ void k_addback(int* __restrict__ excl, const int* __restrict__ boffs,
                          int N, int* __restrict__ cursor)
{
    const int i = blockIdx.x * blockDim.x + threadIdx.x;
    if (i < N) {
        const int v = excl[i] + boffs[i >> 10];
        excl[i] = v;
        cursor[i] = v;
    }
}

__global__ void k_scatter(const int* __restrict__ ei, int E,
                          int* __restrict__ cursor, int* __restrict__ col)
{
    const int e = blockIdx.x * blockDim.x + threadIdx.x;
    if (e < E) {
        const int s = ei[e];
        const int d = ei[E + e];
        const int pos = atomicAdd(&cursor[s], 1);
        col[pos] = d;
    }
}

// ---------------------------------------------------------------------------
// K5: per-node segment softmax + aggregation. block = 4 waves (one per head).
// Fast path deg<=64: scores fully in registers, one pass.
// ---------------------------------------------------------------------------
__global__ __launch_bounds__(256) void k_agg(
    const int* __restrict__ row_start, const int* __restrict__ cnt,
    const int* __restrict__ col, const ushort* __restrict__ hp,
    const float* __restrict__ s_src, const float* __restrict__ s_dst,
    const float* __restrict__ bias, float* __restrict__ out, int N)
{
    __shared__ float l_acc[NH][64];
    __shared__ float l_alpha[NH][64];
    __shared__ int   l_dst[NH][64];

    const int n     = blockIdx.x;
    const int head  = threadIdx.x >> 6;
    const int lane  = threadIdx.x & 63;
    const int start = row_start[n];
    const int deg   = cnt[n];

    const float ssn = s_src[(size_t)head * N + n];
    const float* sdh = s_dst + (size_t)head * N;
    const ushort* hph = hp + (size_t)head * N * FOUT;

    float acc = 0.f;
    if (deg <= 64) {
        int dreg = 0;
        float x = -FLT_MAX;
        if (lane < deg) {
            dreg = col[start + lane];
            const float t = ssn + sdh[dreg];
            x = (t >= 0.f) ? t : NEG_SLOPE * t;
        }
        float m = x;
#pragma unroll
        for (int d = 32; d; d >>= 1) m = fmaxf(m, __shfl_xor(m, d));
        const float e = (lane < deg) ? __expf(x - m) : 0.f;
        float s = e;
#pragma unroll
        for (int d = 32; d; d >>= 1) s += __shfl_xor(s, d);
        const float alpha = e / s;
        for (int jj = 0; jj < deg; ++jj) {
            const float a = __shfl(alpha, jj);
            const int  dd = __shfl(dreg, jj);
            acc = fmaf(a, bf2f(hph[(size_t)dd * FOUT + lane]), acc);
        }
    } else {
        // slow path (rare): 3-pass LDS
        float m = -FLT_MAX;
        for (int j0 = 0; j0 < deg; j0 += 64) {
            const int j = j0 + lane;
            float sc = -FLT_MAX;
            if (j < deg) {
                const int d = col[start + j];
                const float x = ssn + sdh[d];
                sc = (x >= 0.f) ? x : NEG_SLOPE * x;
            }
            m = fmaxf(m, sc);
        }
#pragma unroll
        for (int d = 32; d; d >>= 1) m = fmaxf(m, __shfl_xor(m, d));

        float sum = 0.f;
        for (int j0 = 0; j0 < deg; j0 += 64) {
            const int j = j0 + lane;
            if (j < deg) {
                const int d = col[start + j];
                float x = ssn + sdh[d];
                x = (x >= 0.f) ? x : NEG_SLOPE * x;
                sum += __expf(x - m);
            }
        }
#pragma unroll
        for (int d = 32; d; d >>= 1) sum += __shfl_xor(sum, d);
        const float inv_denom = 1.0f / sum;

        for (int j0 = 0; j0 < deg; j0 += 64) {
            const int j = j0 + lane;
            const int chunk = min(64, deg - j0);
            if (j < deg) {
                const int d = col[start + j];
                float x = ssn + sdh[d];
                x = (x >= 0.f) ? x : NEG_SLOPE * x;
                l_alpha[head][lane] = __expf(x - m) * inv_denom;
                l_dst[head][lane] = d;
            }
            for (int jj = 0; jj < chunk; ++jj) {
                const float a = l_alpha[head][jj];
                const int  dd = l_dst[head][jj];
                acc = fmaf(a, bf2f(hph[(size_t)dd * FOUT + lane]), acc);
            }
        }
    }

    l_acc[head][lane] = acc;
    __syncthreads();
    if (head == 0) {
        out[(size_t)n * FOUT + lane] =
            (l_acc[0][lane] + l_acc[1][lane] + l_acc[2][lane] + l_acc[3][lane])
                * 0.25f + bias[lane];
    }
}

// ---------------------------------------------------------------------------
extern "C" void kernel_launch(void* const* d_in, const int* in_sizes, int n_in,
                              void* d_out, int out_size, void* d_ws, size_t ws_size,
                              hipStream_t stream)
{
    const float* h    = (const float*)d_in[0];
    const int*   ei   = (const int*)d_in[1];
    const float* w    = (const float*)d_in[2];
    const float* fc   = (const float*)d_in[3];
    const float* bias = (const float*)d_in[4];
    float* out = (float*)d_out;

    const int N = in_sizes[0] / FIN;
    const int E = in_sizes[1] / 2;

    char* ws = (char*)d_ws;
    auto take = [&](size_t bytes) {
        char* p = ws;
        ws += (bytes + 255) & ~(size_t)255;
        return p;
    };
    ushort* wt       = (ushort*)take((size_t)NH * FIN * FOUT * sizeof(ushort));
    ushort* h_prime  = (ushort*)take((size_t)NH * N * FOUT * sizeof(ushort));
    float* s_src     = (float*)take((size_t)NH * N * sizeof(float));
    float* s_dst     = (float*)take((size_t)NH * N * sizeof(float));
    int*   cnt       = (int*)take((size_t)N * sizeof(int));
    int*   row_start = (int*)take((size_t)N * sizeof(int));
    int*   cursor    = (int*)take((size_t)N * sizeof(int));
    int*   col       = (int*)take((size_t)E * sizeof(int));
    const int nb = (N + 1023) / 1024;
    int*   bsum      = (int*)take((size_t)nb * sizeof(int));
    int*   boffs     = (int*)take((size_t)nb * sizeof(int));

    hipMemsetAsync(cnt, 0, (size_t)N * sizeof(int), stream);

    k_wconv<<<256, 256, 0, stream>>>(w, wt);
    k_gemm<<<(N + 63) / 64, 256, 0, stream>>>(h, wt, fc, h_prime, s_src, s_dst, N);
    k_hist<<<(E + 255) / 256, 256, 0, stream>>>(ei, E, cnt);
    k_scan_a<<<nb, 1024, 0, stream>>>(cnt, N, row_start, bsum);
    k_scan_b<<<1, 64, 0, stream>>>(bsum, nb, boffs);
    k_addback<<<(N + 255) / 256, 256, 0, stream>>>(row_start, boffs, N, cursor);
    k_scatter<<<(E + 255) / 256, 256, 0, stream>>>(ei, E, cursor, col);
    k_agg<<<N, 256, 0, stream>>>(row_start, cnt, col, h_prime, s_src, s_dst,
                                 bias, out, N);
}

// Round 3
// 226.930 us; speedup vs baseline: 1.8929x; 1.5138x over previous
//
#include <hip/hip_runtime.h>
#include <cfloat>

#define FIN 256
#define FOUT 64
#define NH 4
#define NEG_SLOPE 0.2f

typedef __bf16 bf16x8 __attribute__((ext_vector_type(8)));
typedef float f32x4 __attribute__((ext_vector_type(4)));

__device__ __forceinline__ ushort f2bf(float f) {
    return (ushort)((__float_as_uint(f) + 0x8000u) >> 16);
}
__device__ __forceinline__ float bf2f(ushort u) {
    return __uint_as_float(((unsigned)u) << 16);
}
__device__ __forceinline__ float lrelu(float x) {
    return (x >= 0.f) ? x : NEG_SLOPE * x;
}

// ---------------------------------------------------------------------------
// K0: wt[h][col][k] (bf16) = w[h][k][col]
// ---------------------------------------------------------------------------
__global__ __launch_bounds__(256) void k_wconv(const float* __restrict__ w,
                                               ushort* __restrict__ wt)
{
    const int g = blockIdx.x * 256 + threadIdx.x;   // grid 256 -> 65536
    const int hh  = g >> 14;
    const int rem = g & 16383;
    const int col = rem >> 8;
    const int k   = rem & 255;
    wt[g] = f2bf(w[(((hh << 8) | k) << 6) | col]);
}

// ---------------------------------------------------------------------------
// K1: bf16 MFMA GEMM. block = 256 = 4 waves (one head each), 64 nodes/block.
// hp layout: [n][f][h]  (head-innermost, 512B per node)
// s_src/s_dst layout: [n][h]  (float4 per node)
// ---------------------------------------------------------------------------
#define ASTRIDE 280
__global__ __launch_bounds__(256) void k_gemm(
    const float* __restrict__ h, const ushort* __restrict__ wt,
    const float* __restrict__ fc, ushort* __restrict__ hp,
    float* __restrict__ s_src, float* __restrict__ s_dst, int N)
{
    __shared__ ushort Alds[64 * ASTRIDE];
    const int tid = threadIdx.x;
    const int n0 = blockIdx.x * 64;

    for (int idx = tid; idx < 64 * 64; idx += 256) {
        const int row  = idx >> 6;
        const int quad = idx & 63;
        const int n = n0 + row;
        float4 v = make_float4(0.f, 0.f, 0.f, 0.f);
        if (n < N) v = ((const float4*)(h + (size_t)n * FIN))[quad];
        ushort4 b;
        b.x = f2bf(v.x); b.y = f2bf(v.y); b.z = f2bf(v.z); b.w = f2bf(v.w);
        *(ushort4*)&Alds[row * ASTRIDE + quad * 4] = b;
    }
    __syncthreads();

    const int head = tid >> 6;
    const int lane = tid & 63;
    const int lrow = lane & 15;
    const int lq   = lane >> 4;

    const ushort* wth = wt + head * (64 * 256);

    f32x4 acc[4][4];
#pragma unroll
    for (int mt = 0; mt < 4; ++mt)
#pragma unroll
        for (int nt = 0; nt < 4; ++nt)
            acc[mt][nt] = (f32x4){0.f, 0.f, 0.f, 0.f};

#pragma unroll
    for (int kt = 0; kt < 8; ++kt) {
        const int kof = kt * 32 + lq * 8;
        bf16x8 af[4];
#pragma unroll
        for (int mt = 0; mt < 4; ++mt)
            af[mt] = *(const bf16x8*)&Alds[(mt * 16 + lrow) * ASTRIDE + kof];
#pragma unroll
        for (int nt = 0; nt < 4; ++nt) {
            const bf16x8 bfr = *(const bf16x8*)&wth[(nt * 16 + lrow) * 256 + kof];
#pragma unroll
            for (int mt = 0; mt < 4; ++mt)
                acc[mt][nt] = __builtin_amdgcn_mfma_f32_16x16x32_bf16(
                    af[mt], bfr, acc[mt][nt], 0, 0, 0);
        }
    }

    float as_[4], ad_[4];
#pragma unroll
    for (int nt = 0; nt < 4; ++nt) {
        as_[nt] = fc[head * 2 * FOUT + nt * 16 + lrow];
        ad_[nt] = fc[head * 2 * FOUT + FOUT + nt * 16 + lrow];
    }
#pragma unroll
    for (int mt = 0; mt < 4; ++mt) {
        const int rbase = n0 + mt * 16 + lq * 4;
#pragma unroll
        for (int r = 0; r < 4; ++r) {
            const int n = rbase + r;
            float ps = 0.f, pd = 0.f;
#pragma unroll
            for (int nt = 0; nt < 4; ++nt) {
                const float v = acc[mt][nt][r];
                ps = fmaf(v, as_[nt], ps);
                pd = fmaf(v, ad_[nt], pd);
                if (n < N)
                    hp[((size_t)n * FOUT + nt * 16 + lrow) * NH + head] = f2bf(v);
            }
            ps += __shfl_xor(ps, 1); pd += __shfl_xor(pd, 1);
            ps += __shfl_xor(ps, 2); pd += __shfl_xor(pd, 2);
            ps += __shfl_xor(ps, 4); pd += __shfl_xor(pd, 4);
            ps += __shfl_xor(ps, 8); pd += __shfl_xor(pd, 8);
            if (lrow == 0 && n < N) {
                s_src[(size_t)n * NH + head] = ps;
                s_dst[(size_t)n * NH + head] = pd;
            }
        }
    }
}

// ---------------------------------------------------------------------------
// CSR build
// ---------------------------------------------------------------------------
__global__ void k_hist(const int* __restrict__ ei, int E, int* __restrict__ cnt)
{
    const int e = blockIdx.x * blockDim.x + threadIdx.x;
    if (e < E) atomicAdd(&cnt[ei[e]], 1);
}

__global__ __launch_bounds__(1024) void k_scan_a(
    const int* __restrict__ cnt, int N, int* __restrict__ excl,
    int* __restrict__ bsum)
{
    __shared__ int wsum[16];
    const int tid  = threadIdx.x;
    const int i    = blockIdx.x * 1024 + tid;
    const int lane = tid & 63;
    const int wid  = tid >> 6;
    const int v = (i < N) ? cnt[i] : 0;
    int x = v;
#pragma unroll
    for (int d = 1; d < 64; d <<= 1) {
        const int t = __shfl_up(x, d);
        if (lane >= d) x += t;
    }
    if (lane == 63) wsum[wid] = x;
    __syncthreads();
    if (wid == 0) {
        const int t = (lane < 16) ? wsum[lane] : 0;
        int y = t;
#pragma unroll
        for (int d = 1; d < 16; d <<= 1) {
            const int u = __shfl_up(y, d);
            if (lane >= d) y += u;
        }
        if (lane < 16) wsum[lane] = y - t;
    }
    __syncthreads();
    x += wsum[wid];
    if (i < N) excl[i] = x - v;
    if (tid == 1023) bsum[blockIdx.x] = x;
}

__global__ __launch_bounds__(64) void k_scan_b(
    const int* __restrict__ bsum, int nb, int* __restrict__ boffs)
{
    const int lane = threadIdx.x;
    int carry = 0;
    for (int base = 0; base < nb; base += 64) {
        const int idx = base + lane;
        const int v = (idx < nb) ? bsum[idx] : 0;
        int x = v;
#pragma unroll
        for (int d = 1; d < 64; d <<= 1) {
            const int t = __shfl_up(x, d);
            if (lane >= d) x += t;
        }
        if (idx < nb) boffs[idx] = carry + x - v;
        carry += __shfl(x, 63);
    }
}

__global__ void k_addback(int* __restrict__ excl, const int* __restrict__ boffs,
                          int N, int* __restrict__ cursor)
{
    const int i = blockIdx.x * blockDim.x + threadIdx.x;
    if (i < N) {
        const int v = excl[i] + boffs[i >> 10];
        excl[i] = v;
        cursor[i] = v;
    }
}

__global__ void k_scatter(const int* __restrict__ ei, int E,
                          int* __restrict__ cursor, int* __restrict__ col)
{
    const int e = blockIdx.x * blockDim.x + threadIdx.x;
    if (e < E) {
        const int s = ei[e];
        const int d = ei[E + e];
        const int pos = atomicAdd(&cursor[s], 1);
        col[pos] = d;
    }
}

// ---------------------------------------------------------------------------
// K5: one WAVE per node; lane = feature; all 4 heads in-lane as float4.
// hp: [n][f][h] bf16 -> per edge one contiguous 512B block (ushort4/lane).
// Gather unrolled x4 -> 4 outstanding 512B loads per wave.
// ---------------------------------------------------------------------------
__global__ __launch_bounds__(256) void k_agg(
    const int* __restrict__ row_start, const int* __restrict__ cnt,
    const int* __restrict__ col, const ushort* __restrict__ hp,
    const float* __restrict__ s_src, const float* __restrict__ s_dst,
    const float* __restrict__ bias, float* __restrict__ out, int N)
{
    const int wid  = threadIdx.x >> 6;
    const int lane = threadIdx.x & 63;
    const int n    = blockIdx.x * 4 + wid;
    if (n >= N) return;

    const int start = row_start[n];
    const int deg   = cnt[n];
    const float4 ssn = ((const float4*)s_src)[n];
    const float4* sd4 = (const float4*)s_dst;

    float4 acc = make_float4(0.f, 0.f, 0.f, 0.f);

    if (deg <= 64) {
        int dreg = 0;
        float4 x = make_float4(-FLT_MAX, -FLT_MAX, -FLT_MAX, -FLT_MAX);
        if (lane < deg) {
            dreg = col[start + lane];
            const float4 sd = sd4[dreg];
            x.x = lrelu(ssn.x + sd.x);
            x.y = lrelu(ssn.y + sd.y);
            x.z = lrelu(ssn.z + sd.z);
            x.w = lrelu(ssn.w + sd.w);
        }
        float4 m = x;
#pragma unroll
        for (int d = 32; d; d >>= 1) {
            m.x = fmaxf(m.x, __shfl_xor(m.x, d));
            m.y = fmaxf(m.y, __shfl_xor(m.y, d));
            m.z = fmaxf(m.z, __shfl_xor(m.z, d));
            m.w = fmaxf(m.w, __shfl_xor(m.w, d));
        }
        float4 e = make_float4(0.f, 0.f, 0.f, 0.f);
        if (lane < deg) {
            e.x = __expf(x.x - m.x);
            e.y = __expf(x.y - m.y);
            e.z = __expf(x.z - m.z);
            e.w = __expf(x.w - m.w);
        }
        float4 s = e;
#pragma unroll
        for (int d = 32; d; d >>= 1) {
            s.x += __shfl_xor(s.x, d);
            s.y += __shfl_xor(s.y, d);
            s.z += __shfl_xor(s.z, d);
            s.w += __shfl_xor(s.w, d);
        }
        float4 alpha;
        alpha.x = e.x / s.x;
        alpha.y = e.y / s.y;
        alpha.z = e.z / s.z;
        alpha.w = e.w / s.w;

        const int full = deg & ~3;
        int jj = 0;
        for (; jj < full; jj += 4) {
            int dd[4];
            float4 av[4];
#pragma unroll
            for (int u = 0; u < 4; ++u) {
                dd[u]   = __shfl(dreg, jj + u);
                av[u].x = __shfl(alpha.x, jj + u);
                av[u].y = __shfl(alpha.y, jj + u);
                av[u].z = __shfl(alpha.z, jj + u);
                av[u].w = __shfl(alpha.w, jj + u);
            }
            ushort4 v[4];
#pragma unroll
            for (int u = 0; u < 4; ++u)
                v[u] = *(const ushort4*)&hp[((size_t)dd[u] * FOUT + lane) * NH];
#pragma unroll
            for (int u = 0; u < 4; ++u) {
                acc.x = fmaf(av[u].x, bf2f(v[u].x), acc.x);
                acc.y = fmaf(av[u].y, bf2f(v[u].y), acc.y);
                acc.z = fmaf(av[u].z, bf2f(v[u].z), acc.z);
                acc.w = fmaf(av[u].w, bf2f(v[u].w), acc.w);
            }
        }
        for (; jj < deg; ++jj) {
            const int ddu = __shfl(dreg, jj);
            float4 av;
            av.x = __shfl(alpha.x, jj);
            av.y = __shfl(alpha.y, jj);
            av.z = __shfl(alpha.z, jj);
            av.w = __shfl(alpha.w, jj);
            const ushort4 v = *(const ushort4*)&hp[((size_t)ddu * FOUT + lane) * NH];
            acc.x = fmaf(av.x, bf2f(v.x), acc.x);
            acc.y = fmaf(av.y, bf2f(v.y), acc.y);
            acc.z = fmaf(av.z, bf2f(v.z), acc.z);
            acc.w = fmaf(av.w, bf2f(v.w), acc.w);
        }
    } else {
        // slow path: chunked 3-pass, same in-lane float4 scheme
        float4 m = make_float4(-FLT_MAX, -FLT_MAX, -FLT_MAX, -FLT_MAX);
        for (int j0 = 0; j0 < deg; j0 += 64) {
            const int j = j0 + lane;
            if (j < deg) {
                const int d = col[start + j];
                const float4 sd = sd4[d];
                m.x = fmaxf(m.x, lrelu(ssn.x + sd.x));
                m.y = fmaxf(m.y, lrelu(ssn.y + sd.y));
                m.z = fmaxf(m.z, lrelu(ssn.z + sd.z));
                m.w = fmaxf(m.w, lrelu(ssn.w + sd.w));
            }
        }
#pragma unroll
        for (int d = 32; d; d >>= 1) {
            m.x = fmaxf(m.x, __shfl_xor(m.x, d));
            m.y = fmaxf(m.y, __shfl_xor(m.y, d));
            m.z = fmaxf(m.z, __shfl_xor(m.z, d));
            m.w = fmaxf(m.w, __shfl_xor(m.w, d));
        }
        float4 s = make_float4(0.f, 0.f, 0.f, 0.f);
        for (int j0 = 0; j0 < deg; j0 += 64) {
            const int j = j0 + lane;
            if (j < deg) {
                const int d = col[start + j];
                const float4 sd = sd4[d];
                s.x += __expf(lrelu(ssn.x + sd.x) - m.x);
                s.y += __expf(lrelu(ssn.y + sd.y) - m.y);
                s.z += __expf(lrelu(ssn.z + sd.z) - m.z);
                s.w += __expf(lrelu(ssn.w + sd.w) - m.w);
            }
        }
#pragma unroll
        for (int d = 32; d; d >>= 1) {
            s.x += __shfl_xor(s.x, d);
            s.y += __shfl_xor(s.y, d);
            s.z += __shfl_xor(s.z, d);
            s.w += __shfl_xor(s.w, d);
        }
        const float4 inv = make_float4(1.f / s.x, 1.f / s.y, 1.f / s.z, 1.f / s.w);

        for (int j0 = 0; j0 < deg; j0 += 64) {
            const int j = j0 + lane;
            const int chunk = min(64, deg - j0);
            int dreg = 0;
            float4 alpha = make_float4(0.f, 0.f, 0.f, 0.f);
            if (j < deg) {
                dreg = col[start + j];
                const float4 sd = sd4[dreg];
                alpha.x = __expf(lrelu(ssn.x + sd.x) - m.x) * inv.x;
                alpha.y = __expf(lrelu(ssn.y + sd.y) - m.y) * inv.y;
                alpha.z = __expf(lrelu(ssn.z + sd.z) - m.z) * inv.z;
                alpha.w = __expf(lrelu(ssn.w + sd.w) - m.w) * inv.w;
            }
            const int full = chunk & ~3;
            int jj = 0;
            for (; jj < full; jj += 4) {
                int dd[4];
                float4 av[4];
#pragma unroll
                for (int u = 0; u < 4; ++u) {
                    dd[u]   = __shfl(dreg, jj + u);
                    av[u].x = __shfl(alpha.x, jj + u);
                    av[u].y = __shfl(alpha.y, jj + u);
                    av[u].z = __shfl(alpha.z, jj + u);
                    av[u].w = __shfl(alpha.w, jj + u);
                }
                ushort4 v[4];
#pragma unroll
                for (int u = 0; u < 4; ++u)
                    v[u] = *(const ushort4*)&hp[((size_t)dd[u] * FOUT + lane) * NH];
#pragma unroll
                for (int u = 0; u < 4; ++u) {
                    acc.x = fmaf(av[u].x, bf2f(v[u].x), acc.x);
                    acc.y = fmaf(av[u].y, bf2f(v[u].y), acc.y);
                    acc.z = fmaf(av[u].z, bf2f(v[u].z), acc.z);
                    acc.w = fmaf(av[u].w, bf2f(v[u].w), acc.w);
                }
            }
            for (; jj < chunk; ++jj) {
                const int ddu = __shfl(dreg, jj);
                float4 av;
                av.x = __shfl(alpha.x, jj);
                av.y = __shfl(alpha.y, jj);
                av.z = __shfl(alpha.z, jj);
                av.w = __shfl(alpha.w, jj);
                const ushort4 v = *(const ushort4*)&hp[((size_t)ddu * FOUT + lane) * NH];
                acc.x = fmaf(av.x, bf2f(v.x), acc.x);
                acc.y = fmaf(av.y, bf2f(v.y), acc.y);
                acc.z = fmaf(av.z, bf2f(v.z), acc.z);
                acc.w = fmaf(av.w, bf2f(v.w), acc.w);
            }
        }
    }

    out[(size_t)n * FOUT + lane] =
        (acc.x + acc.y + acc.z + acc.w) * 0.25f + bias[lane];
}

// ---------------------------------------------------------------------------
extern "C" void kernel_launch(void* const* d_in, const int* in_sizes, int n_in,
                              void* d_out, int out_size, void* d_ws, size_t ws_size,
                              hipStream_t stream)
{
    const float* h    = (const float*)d_in[0];
    const int*   ei   = (const int*)d_in[1];
    const float* w    = (const float*)d_in[2];
    const float* fc   = (const float*)d_in[3];
    const float* bias = (const float*)d_in[4];
    float* out = (float*)d_out;

    const int N = in_sizes[0] / FIN;
    const int E = in_sizes[1] / 2;

    char* ws = (char*)d_ws;
    auto take = [&](size_t bytes) {
        char* p = ws;
        ws += (bytes + 255) & ~(size_t)255;
        return p;
    };
    ushort* wt       = (ushort*)take((size_t)NH * FIN * FOUT * sizeof(ushort));
    ushort* h_prime  = (ushort*)take((size_t)NH * N * FOUT * sizeof(ushort));
    float* s_src     = (float*)take((size_t)NH * N * sizeof(float));
    float* s_dst     = (float*)take((size_t)NH * N * sizeof(float));
    int*   cnt       = (int*)take((size_t)N * sizeof(int));
    int*   row_start = (int*)take((size_t)N * sizeof(int));
    int*   cursor    = (int*)take((size_t)N * sizeof(int));
    int*   col       = (int*)take((size_t)E * sizeof(int));
    const int nb = (N + 1023) / 1024;
    int*   bsum      = (int*)take((size_t)nb * sizeof(int));
    int*   boffs     = (int*)take((size_t)nb * sizeof(int));

    hipMemsetAsync(cnt, 0, (size_t)N * sizeof(int), stream);

    k_wconv<<<256, 256, 0, stream>>>(w, wt);
    k_gemm<<<(N + 63) / 64, 256, 0, stream>>>(h, wt, fc, h_prime, s_src, s_dst, N);
    k_hist<<<(E + 255) / 256, 256, 0, stream>>>(ei, E, cnt);
    k_scan_a<<<nb, 1024, 0, stream>>>(cnt, N, row_start, bsum);
    k_scan_b<<<1, 64, 0, stream>>>(bsum, nb, boffs);
    k_addback<<<(N + 255) / 256, 256, 0, stream>>>(row_start, boffs, N, cursor);
    k_scatter<<<(E + 255) / 256, 256, 0, stream>>>(ei, E, cursor, col);
    k_agg<<<(N + 3) / 4, 256, 0, stream>>>(row_start, cnt, col, h_prime,
                                           s_src, s_dst, bias, out, N);
}

// Round 4
// 220.381 us; speedup vs baseline: 1.9492x; 1.0297x over previous
//
#include <hip/hip_runtime.h>
#include <cfloat>

#define FIN 256
#define FOUT 64
#define NH 4
#define NEG_SLOPE 0.2f

typedef __bf16 bf16x8 __attribute__((ext_vector_type(8)));
typedef float f32x4 __attribute__((ext_vector_type(4)));

__device__ __forceinline__ ushort f2bf(float f) {
    return (ushort)((__float_as_uint(f) + 0x8000u) >> 16);
}
__device__ __forceinline__ float bf2f(ushort u) {
    return __uint_as_float(((unsigned)u) << 16);
}
__device__ __forceinline__ float lrelu(float x) {
    return (x >= 0.f) ? x : NEG_SLOPE * x;
}

// ---------------------------------------------------------------------------
// K0: wt[h][col][k] (bf16) = w[h][k][col]
// ---------------------------------------------------------------------------
__global__ __launch_bounds__(256) void k_wconv(const float* __restrict__ w,
                                               ushort* __restrict__ wt)
{
    const int g = blockIdx.x * 256 + threadIdx.x;   // grid 256 -> 65536
    const int hh  = g >> 14;
    const int rem = g & 16383;
    const int col = rem >> 8;
    const int k   = rem & 255;
    wt[g] = f2bf(w[(((hh << 8) | k) << 6) | col]);
}

// ---------------------------------------------------------------------------
// K1: bf16 MFMA GEMM. block = 256 = 4 waves (one head each), 64 nodes/block.
// hp layout: [n][f][h] (head-innermost, 512B/node), written coalesced via an
// LDS transpose tile. s_src/s_dst: [n][h] float4.
// ---------------------------------------------------------------------------
#define ASTRIDE 280   // staging row stride (ushorts)
#define OSTRIDE 260   // out-tile row stride (ushorts): 2 lanes/bank on writes
__global__ __launch_bounds__(256) void k_gemm(
    const float* __restrict__ h, const ushort* __restrict__ wt,
    const float* __restrict__ fc, ushort* __restrict__ hp,
    float* __restrict__ s_src, float* __restrict__ s_dst, int N)
{
    __shared__ ushort Alds[64 * ASTRIDE];
    const int tid = threadIdx.x;
    const int n0 = blockIdx.x * 64;

    for (int idx = tid; idx < 64 * 64; idx += 256) {
        const int row  = idx >> 6;
        const int quad = idx & 63;
        const int n = n0 + row;
        float4 v = make_float4(0.f, 0.f, 0.f, 0.f);
        if (n < N) v = ((const float4*)(h + (size_t)n * FIN))[quad];
        ushort4 b;
        b.x = f2bf(v.x); b.y = f2bf(v.y); b.z = f2bf(v.z); b.w = f2bf(v.w);
        *(ushort4*)&Alds[row * ASTRIDE + quad * 4] = b;
    }
    __syncthreads();

    const int head = tid >> 6;
    const int lane = tid & 63;
    const int lrow = lane & 15;
    const int lq   = lane >> 4;

    const ushort* wth = wt + head * (64 * 256);

    f32x4 acc[4][4];
#pragma unroll
    for (int mt = 0; mt < 4; ++mt)
#pragma unroll
        for (int nt = 0; nt < 4; ++nt)
            acc[mt][nt] = (f32x4){0.f, 0.f, 0.f, 0.f};

#pragma unroll
    for (int kt = 0; kt < 8; ++kt) {
        const int kof = kt * 32 + lq * 8;
        bf16x8 af[4];
#pragma unroll
        for (int mt = 0; mt < 4; ++mt)
            af[mt] = *(const bf16x8*)&Alds[(mt * 16 + lrow) * ASTRIDE + kof];
#pragma unroll
        for (int nt = 0; nt < 4; ++nt) {
            const bf16x8 bfr = *(const bf16x8*)&wth[(nt * 16 + lrow) * 256 + kof];
#pragma unroll
            for (int mt = 0; mt < 4; ++mt)
                acc[mt][nt] = __builtin_amdgcn_mfma_f32_16x16x32_bf16(
                    af[mt], bfr, acc[mt][nt], 0, 0, 0);
        }
    }

    // ---- epilogue A: s_src/s_dst via 16-lane shuffle reduce (no LDS) ----
    float as_[4], ad_[4];
#pragma unroll
    for (int nt = 0; nt < 4; ++nt) {
        as_[nt] = fc[head * 2 * FOUT + nt * 16 + lrow];
        ad_[nt] = fc[head * 2 * FOUT + FOUT + nt * 16 + lrow];
    }
#pragma unroll
    for (int mt = 0; mt < 4; ++mt) {
        const int rbase = n0 + mt * 16 + lq * 4;
#pragma unroll
        for (int r = 0; r < 4; ++r) {
            const int n = rbase + r;
            float ps = 0.f, pd = 0.f;
#pragma unroll
            for (int nt = 0; nt < 4; ++nt) {
                const float v = acc[mt][nt][r];
                ps = fmaf(v, as_[nt], ps);
                pd = fmaf(v, ad_[nt], pd);
            }
            ps += __shfl_xor(ps, 1); pd += __shfl_xor(pd, 1);
            ps += __shfl_xor(ps, 2); pd += __shfl_xor(pd, 2);
            ps += __shfl_xor(ps, 4); pd += __shfl_xor(pd, 4);
            ps += __shfl_xor(ps, 8); pd += __shfl_xor(pd, 8);
            if (lrow == 0 && n < N) {
                s_src[(size_t)n * NH + head] = ps;
                s_dst[(size_t)n * NH + head] = pd;
            }
        }
    }

    // ---- epilogue B: hp via LDS transpose, coalesced ushort4 stores ----
    __syncthreads();   // all waves done reading A-tile
#pragma unroll
    for (int mt = 0; mt < 4; ++mt)
#pragma unroll
        for (int r = 0; r < 4; ++r)
#pragma unroll
            for (int nt = 0; nt < 4; ++nt)
                Alds[(mt * 16 + lq * 4 + r) * OSTRIDE +
                     (nt * 16 + lrow) * 4 + head] = f2bf(acc[mt][nt][r]);
    __syncthreads();
    for (int idx = tid; idx < 64 * 64; idx += 256) {
        const int row = idx >> 6;
        const int c   = idx & 63;
        const int n = n0 + row;
        if (n < N)
            *(ushort4*)&hp[(size_t)n * 256 + c * 4] =
                *(const ushort4*)&Alds[row * OSTRIDE + c * 4];
    }
}

// ---------------------------------------------------------------------------
// CSR build
// ---------------------------------------------------------------------------
__global__ void k_hist(const int* __restrict__ ei, int E, int* __restrict__ cnt)
{
    const int e = blockIdx.x * blockDim.x + threadIdx.x;
    if (e < E) atomicAdd(&cnt[ei[e]], 1);
}

__global__ __launch_bounds__(1024) void k_scan_a(
    const int* __restrict__ cnt, int N, int* __restrict__ excl,
    int* __restrict__ bsum)
{
    __shared__ int wsum[16];
    const int tid  = threadIdx.x;
    const int i    = blockIdx.x * 1024 + tid;
    const int lane = tid & 63;
    const int wid  = tid >> 6;
    const int v = (i < N) ? cnt[i] : 0;
    int x = v;
#pragma unroll
    for (int d = 1; d < 64; d <<= 1) {
        const int t = __shfl_up(x, d);
        if (lane >= d) x += t;
    }
    if (lane == 63) wsum[wid] = x;
    __syncthreads();
    if (wid == 0) {
        const int t = (lane < 16) ? wsum[lane] : 0;
        int y = t;
#pragma unroll
        for (int d = 1; d < 16; d <<= 1) {
            const int u = __shfl_up(y, d);
            if (lane >= d) y += u;
        }
        if (lane < 16) wsum[lane] = y - t;
    }
    __syncthreads();
    x += wsum[wid];
    if (i < N) excl[i] = x - v;
    if (tid == 1023) bsum[blockIdx.x] = x;
}

__global__ __launch_bounds__(64) void k_scan_b(
    const int* __restrict__ bsum, int nb, int* __restrict__ boffs)
{
    const int lane = threadIdx.x;
    int carry = 0;
    for (int base = 0; base < nb; base += 64) {
        const int idx = base + lane;
        const int v = (idx < nb) ? bsum[idx] : 0;
        int x = v;
#pragma unroll
        for (int d = 1; d < 64; d <<= 1) {
            const int t = __shfl_up(x, d);
            if (lane >= d) x += t;
        }
        if (idx < nb) boffs[idx] = carry + x - v;
        carry += __shfl(x, 63);
    }
}

__global__ void k_addback(int* __restrict__ excl, const int* __restrict__ boffs,
                          int N, int* __restrict__ cursor)
{
    const int i = blockIdx.x * blockDim.x + threadIdx.x;
    if (i < N) {
        const int v = excl[i] + boffs[i >> 10];
        excl[i] = v;
        cursor[i] = v;
    }
}

__global__ void k_scatter(const int* __restrict__ ei, int E,
                          int* __restrict__ cursor, int* __restrict__ col)
{
    const int e = blockIdx.x * blockDim.x + threadIdx.x;
    if (e < E) {
        const int s = ei[e];
        const int d = ei[E + e];
        const int pos = atomicAdd(&cursor[s], 1);
        col[pos] = d;
    }
}

// ---------------------------------------------------------------------------
// K5: one WAVE per node; lane = feature; 4 heads in-lane as float4.
// Fast path deg<=64: softmax in registers; gather double-buffered x4 so
// 4-8 x 512B loads stay outstanding continuously.
// ---------------------------------------------------------------------------
__global__ __launch_bounds__(256) void k_agg(
    const int* __restrict__ row_start, const int* __restrict__ cnt,
    const int* __restrict__ col, const ushort* __restrict__ hp,
    const float* __restrict__ s_src, const float* __restrict__ s_dst,
    const float* __restrict__ bias, float* __restrict__ out, int N)
{
    const int wid  = threadIdx.x >> 6;
    const int lane = threadIdx.x & 63;
    const int n    = blockIdx.x * 4 + wid;
    if (n >= N) return;

    const int start = row_start[n];
    const int deg   = cnt[n];
    const float4 ssn = ((const float4*)s_src)[n];
    const float4* sd4 = (const float4*)s_dst;

    float4 acc = make_float4(0.f, 0.f, 0.f, 0.f);

    if (deg <= 64) {
        int dreg = 0;
        float4 x = make_float4(-FLT_MAX, -FLT_MAX, -FLT_MAX, -FLT_MAX);
        if (lane < deg) {
            dreg = col[start + lane];
            const float4 sd = sd4[dreg];
            x.x = lrelu(ssn.x + sd.x);
            x.y = lrelu(ssn.y + sd.y);
            x.z = lrelu(ssn.z + sd.z);
            x.w = lrelu(ssn.w + sd.w);
        }
        float4 m = x;
#pragma unroll
        for (int d = 32; d; d >>= 1) {
            m.x = fmaxf(m.x, __shfl_xor(m.x, d));
            m.y = fmaxf(m.y, __shfl_xor(m.y, d));
            m.z = fmaxf(m.z, __shfl_xor(m.z, d));
            m.w = fmaxf(m.w, __shfl_xor(m.w, d));
        }
        float4 e = make_float4(0.f, 0.f, 0.f, 0.f);
        if (lane < deg) {
            e.x = __expf(x.x - m.x);
            e.y = __expf(x.y - m.y);
            e.z = __expf(x.z - m.z);
            e.w = __expf(x.w - m.w);
        }
        float4 s = e;
#pragma unroll
        for (int d = 32; d; d >>= 1) {
            s.x += __shfl_xor(s.x, d);
            s.y += __shfl_xor(s.y, d);
            s.z += __shfl_xor(s.z, d);
            s.w += __shfl_xor(s.w, d);
        }
        float4 alpha;   // lanes >= deg have e=0 -> alpha=0 (zero-pad)
        alpha.x = e.x / s.x;
        alpha.y = e.y / s.y;
        alpha.z = e.z / s.z;
        alpha.w = e.w / s.w;

        // double-buffered gather, blocks of 4 edges, zero-padded
        const int nblk = (deg + 3) >> 2;
        int dd[4]; float4 av[4]; ushort4 v[4];
#pragma unroll
        for (int u = 0; u < 4; ++u) {
            dd[u]   = __shfl(dreg, u);
            av[u].x = __shfl(alpha.x, u);
            av[u].y = __shfl(alpha.y, u);
            av[u].z = __shfl(alpha.z, u);
            av[u].w = __shfl(alpha.w, u);
        }
#pragma unroll
        for (int u = 0; u < 4; ++u)
            v[u] = *(const ushort4*)&hp[((size_t)dd[u] * FOUT + lane) * NH];

        for (int b = 1; b < nblk; ++b) {
            int dd2[4]; float4 av2[4]; ushort4 v2[4];
#pragma unroll
            for (int u = 0; u < 4; ++u) {
                const int j = b * 4 + u;
                dd2[u]   = __shfl(dreg, j);
                av2[u].x = __shfl(alpha.x, j);
                av2[u].y = __shfl(alpha.y, j);
                av2[u].z = __shfl(alpha.z, j);
                av2[u].w = __shfl(alpha.w, j);
            }
#pragma unroll
            for (int u = 0; u < 4; ++u)
                v2[u] = *(const ushort4*)&hp[((size_t)dd2[u] * FOUT + lane) * NH];
#pragma unroll
            for (int u = 0; u < 4; ++u) {
                acc.x = fmaf(av[u].x, bf2f(v[u].x), acc.x);
                acc.y = fmaf(av[u].y, bf2f(v[u].y), acc.y);
                acc.z = fmaf(av[u].z, bf2f(v[u].z), acc.z);
                acc.w = fmaf(av[u].w, bf2f(v[u].w), acc.w);
            }
#pragma unroll
            for (int u = 0; u < 4; ++u) {
                dd[u] = dd2[u]; av[u] = av2[u]; v[u] = v2[u];
            }
        }
#pragma unroll
        for (int u = 0; u < 4; ++u) {
            acc.x = fmaf(av[u].x, bf2f(v[u].x), acc.x);
            acc.y = fmaf(av[u].y, bf2f(v[u].y), acc.y);
            acc.z = fmaf(av[u].z, bf2f(v[u].z), acc.z);
            acc.w = fmaf(av[u].w, bf2f(v[u].w), acc.w);
        }
    } else {
        // slow path: chunked 3-pass
        float4 m = make_float4(-FLT_MAX, -FLT_MAX, -FLT_MAX, -FLT_MAX);
        for (int j0 = 0; j0 < deg; j0 += 64) {
            const int j = j0 + lane;
            if (j < deg) {
                const int d = col[start + j];
                const float4 sd = sd4[d];
                m.x = fmaxf(m.x, lrelu(ssn.x + sd.x));
                m.y = fmaxf(m.y, lrelu(ssn.y + sd.y));
                m.z = fmaxf(m.z, lrelu(ssn.z + sd.z));
                m.w = fmaxf(m.w, lrelu(ssn.w + sd.w));
            }
        }
#pragma unroll
        for (int d = 32; d; d >>= 1) {
            m.x = fmaxf(m.x, __shfl_xor(m.x, d));
            m.y = fmaxf(m.y, __shfl_xor(m.y, d));
            m.z = fmaxf(m.z, __shfl_xor(m.z, d));
            m.w = fmaxf(m.w, __shfl_xor(m.w, d));
        }
        float4 s = make_float4(0.f, 0.f, 0.f, 0.f);
        for (int j0 = 0; j0 < deg; j0 += 64) {
            const int j = j0 + lane;
            if (j < deg) {
                const int d = col[start + j];
                const float4 sd = sd4[d];
                s.x += __expf(lrelu(ssn.x + sd.x) - m.x);
                s.y += __expf(lrelu(ssn.y + sd.y) - m.y);
                s.z += __expf(lrelu(ssn.z + sd.z) - m.z);
                s.w += __expf(lrelu(ssn.w + sd.w) - m.w);
            }
        }
#pragma unroll
        for (int d = 32; d; d >>= 1) {
            s.x += __shfl_xor(s.x, d);
            s.y += __shfl_xor(s.y, d);
            s.z += __shfl_xor(s.z, d);
            s.w += __shfl_xor(s.w, d);
        }
        const float4 inv = make_float4(1.f / s.x, 1.f / s.y, 1.f / s.z, 1.f / s.w);

        for (int j0 = 0; j0 < deg; j0 += 64) {
            const int j = j0 + lane;
            const int chunk = min(64, deg - j0);
            int dreg = 0;
            float4 alpha = make_float4(0.f, 0.f, 0.f, 0.f);
            if (j < deg) {
                dreg = col[start + j];
                const float4 sd = sd4[dreg];
                alpha.x = __expf(lrelu(ssn.x + sd.x) - m.x) * inv.x;
                alpha.y = __expf(lrelu(ssn.y + sd.y) - m.y) * inv.y;
                alpha.z = __expf(lrelu(ssn.z + sd.z) - m.z) * inv.z;
                alpha.w = __expf(lrelu(ssn.w + sd.w) - m.w) * inv.w;
            }
            const int nblk = (chunk + 3) >> 2;
            int dd[4]; float4 av[4]; ushort4 v[4];
#pragma unroll
            for (int u = 0; u < 4; ++u) {
                dd[u]   = __shfl(dreg, u);
                av[u].x = __shfl(alpha.x, u);
                av[u].y = __shfl(alpha.y, u);
                av[u].z = __shfl(alpha.z, u);
                av[u].w = __shfl(alpha.w, u);
            }
#pragma unroll
            for (int u = 0; u < 4; ++u)
                v[u] = *(const ushort4*)&hp[((size_t)dd[u] * FOUT + lane) * NH];
            for (int b = 1; b < nblk; ++b) {
                int dd2[4]; float4 av2[4]; ushort4 v2[4];
#pragma unroll
                for (int u = 0; u < 4; ++u) {
                    const int jj = b * 4 + u;
                    dd2[u]   = __shfl(dreg, jj);
                    av2[u].x = __shfl(alpha.x, jj);
                    av2[u].y = __shfl(alpha.y, jj);
                    av2[u].z = __shfl(alpha.z, jj);
                    av2[u].w = __shfl(alpha.w, jj);
                }
#pragma unroll
                for (int u = 0; u < 4; ++u)
                    v2[u] = *(const ushort4*)&hp[((size_t)dd2[u] * FOUT + lane) * NH];
#pragma unroll
                for (int u = 0; u < 4; ++u) {
                    acc.x = fmaf(av[u].x, bf2f(v[u].x), acc.x);
                    acc.y = fmaf(av[u].y, bf2f(v[u].y), acc.y);
                    acc.z = fmaf(av[u].z, bf2f(v[u].z), acc.z);
                    acc.w = fmaf(av[u].w, bf2f(v[u].w), acc.w);
                }
#pragma unroll
                for (int u = 0; u < 4; ++u) {
                    dd[u] = dd2[u]; av[u] = av2[u]; v[u] = v2[u];
                }
            }
#pragma unroll
            for (int u = 0; u < 4; ++u) {
                acc.x = fmaf(av[u].x, bf2f(v[u].x), acc.x);
                acc.y = fmaf(av[u].y, bf2f(v[u].y), acc.y);
                acc.z = fmaf(av[u].z, bf2f(v[u].z), acc.z);
                acc.w = fmaf(av[u].w, bf2f(v[u].w), acc.w);
            }
        }
    }

    out[(size_t)n * FOUT + lane] =
        (acc.x + acc.y + acc.z + acc.w) * 0.25f + bias[lane];
}

// ---------------------------------------------------------------------------
extern "C" void kernel_launch(void* const* d_in, const int* in_sizes, int n_in,
                              void* d_out, int out_size, void* d_ws, size_t ws_size,
                              hipStream_t stream)
{
    const float* h    = (const float*)d_in[0];
    const int*   ei   = (const int*)d_in[1];
    const float* w    = (const float*)d_in[2];
    const float* fc   = (const float*)d_in[3];
    const float* bias = (const float*)d_in[4];
    float* out = (float*)d_out;

    const int N = in_sizes[0] / FIN;
    const int E = in_sizes[1] / 2;

    char* ws = (char*)d_ws;
    auto take = [&](size_t bytes) {
        char* p = ws;
        ws += (bytes + 255) & ~(size_t)255;
        return p;
    };
    ushort* wt       = (ushort*)take((size_t)NH * FIN * FOUT * sizeof(ushort));
    ushort* h_prime  = (ushort*)take((size_t)NH * N * FOUT * sizeof(ushort));
    float* s_src     = (float*)take((size_t)NH * N * sizeof(float));
    float* s_dst     = (float*)take((size_t)NH * N * sizeof(float));
    int*   cnt       = (int*)take((size_t)N * sizeof(int));
    int*   row_start = (int*)take((size_t)N * sizeof(int));
    int*   cursor    = (int*)take((size_t)N * sizeof(int));
    int*   col       = (int*)take((size_t)E * sizeof(int));
    const int nb = (N + 1023) / 1024;
    int*   bsum      = (int*)take((size_t)nb * sizeof(int));
    int*   boffs     = (int*)take((size_t)nb * sizeof(int));

    hipMemsetAsync(cnt, 0, (size_t)N * sizeof(int), stream);

    k_wconv<<<256, 256, 0, stream>>>(w, wt);
    k_gemm<<<(N + 63) / 64, 256, 0, stream>>>(h, wt, fc, h_prime, s_src, s_dst, N);
    k_hist<<<(E + 255) / 256, 256, 0, stream>>>(ei, E, cnt);
    k_scan_a<<<nb, 1024, 0, stream>>>(cnt, N, row_start, bsum);
    k_scan_b<<<1, 64, 0, stream>>>(bsum, nb, boffs);
    k_addback<<<(N + 255) / 256, 256, 0, stream>>>(row_start, boffs, N, cursor);
    k_scatter<<<(E + 255) / 256, 256, 0, stream>>>(ei, E, cursor, col);
    k_agg<<<(N + 3) / 4, 256, 0, stream>>>(row_start, cnt, col, h_prime,
                                           s_src, s_dst, bias, out, N);
}